// Round 18
// baseline (255.609 us; speedup 1.0000x reference)
//
#include <hip/hip_runtime.h>
#include <hip/hip_bf16.h>

// WindowAttention: B=128 windows, N=512, C=256, H=8, D=32.
// Round 18: dispatch-order swap in fused kernel — qkv blocks 0..1535 start
// first (MFMA critical path), cmb blocks 1536..1791 fill behind. Bodies
// byte-identical to R17. attn FROZEN byte-identical (R6 lineage; 4/4
// structural edits NaN'd — codegen-sensitive). proj/cpb byte-identical to R17.
// ws layout (bytes):
//   qbuf  bf16 (B,H,N,D)  @ 0           33,554,432  (q pre-scaled by 1/sqrt(32)*log2e; overwritten by attn out)
//   kbuf  bf16 (B,H,N,D)  @ 33,554,432  33,554,432
//   vbuf  bf16 (B,H,N,D)  @ 67,108,864  33,554,432
//   cmb   bf16 (16,8,N,N) @ 100,663,296 67,108,864  (16*sigmoid*log2e + mask*log2e - 11.65, centered)
//   tbl   f32  (3375,8)   @ 167,772,160    108,000
// total ~167.9 MB

using u16 = unsigned short;
using u32 = unsigned int;
typedef short bf16x4 __attribute__((ext_vector_type(4)));
typedef short bf16x8 __attribute__((ext_vector_type(8)));
typedef float f32x4 __attribute__((ext_vector_type(4)));

#define QSL 0.25503471f       // (1/sqrt(32)) * log2(e)
#define LOG2E 1.44269504f
#define CMB_SHIFT 11.65f      // centers bias*log2e (~11.66); softmax shift-invariant

static __device__ __forceinline__ u32 cvt_pk_bf16(float lo, float hi) {
  u32 r;
  asm("v_cvt_pk_bf16_f32 %0, %1, %2" : "=v"(r) : "v"(lo), "v"(hi));
  return r;
}

// ---------------- kernel 1: CPB MLP -> 16*sigmoid*log2e table ----------------
// grid 422: each block computes 8 table rows; w1/b1/w2 slices hoisted out of
// the p-loop (loop-invariant). Same arithmetic per element as before.
__global__ __launch_bounds__(512) void cpb_kernel(
    const float* __restrict__ rpb, const float* __restrict__ w1,
    const float* __restrict__ b1, const float* __restrict__ w2,
    float* __restrict__ table16) {
  __shared__ float hid[512];
  const int p0 = blockIdx.x * 8;  // 0..3368
  const int t = threadIdx.x;      // 0..511
  const float w10 = w1[t * 3 + 0], w11 = w1[t * 3 + 1], w12 = w1[t * 3 + 2];
  const float bb = b1[t];
  const int h = t >> 6, lane = t & 63;  // 8 waves, one head per wave
  float w2r[8];
#pragma unroll
  for (int u = 0; u < 8; ++u) w2r[u] = w2[h * 512 + lane + u * 64];
#pragma unroll
  for (int pp = 0; pp < 8; ++pp) {
    const int p = p0 + pp;
    if (p >= 3375) break;  // uniform within block
    const float r0 = rpb[p * 3 + 0], r1 = rpb[p * 3 + 1], r2 = rpb[p * 3 + 2];
    const float hv = fmaf(r0, w10, fmaf(r1, w11, fmaf(r2, w12, bb)));
    __syncthreads();  // prior iteration's reduce reads of hid done
    hid[t] = fmaxf(hv, 0.0f);
    __syncthreads();
    float s = 0.0f;
#pragma unroll
    for (int u = 0; u < 8; ++u)
      s = fmaf(hid[lane + u * 64], w2r[u], s);
#pragma unroll
    for (int off = 32; off > 0; off >>= 1) s += __shfl_down(s, off);
    if (lane == 0) table16[p * 8 + h] = 23.08312065f / (1.0f + __expf(-s));  // 16*log2e*sigmoid
  }
}

// ---------------- kernel 2: fused qkv + cmb ----------------
// blocks 0..1535: qkv GEMM bn-pair merged + A-prefetch (dispatched first).
// blocks 1536..1791: cmb (combined centered bias+mask, bf16).
__global__ __launch_bounds__(256, 2) void cmb_qkv_fused(
    const int* __restrict__ rpb_idx, const float* __restrict__ table16,
    const float* __restrict__ mask, u16* __restrict__ cmb,
    const float* __restrict__ x, const float* __restrict__ w,
    u16* __restrict__ qbuf, u16* __restrict__ kbuf, u16* __restrict__ vbuf) {
  __shared__ u16 As[128 * 64];
  __shared__ u16 Bs0[128 * 64];
  __shared__ u16 Bs1[128 * 64];
  const int tid = threadIdx.x;

  if (blockIdx.x >= 1536) {
    // ---- cmb body (byte-identical logic to R17) ----
    const int ij0 = ((blockIdx.x - 1536) * 256 + tid) * 4;  // 0..262140
    const int4 i4 = *reinterpret_cast<const int4*>(rpb_idx + ij0);
    float ta[8], tb[8], tc[8], td[8];
    *reinterpret_cast<float4*>(&ta[0]) = *reinterpret_cast<const float4*>(table16 + i4.x * 8);
    *reinterpret_cast<float4*>(&ta[4]) = *reinterpret_cast<const float4*>(table16 + i4.x * 8 + 4);
    *reinterpret_cast<float4*>(&tb[0]) = *reinterpret_cast<const float4*>(table16 + i4.y * 8);
    *reinterpret_cast<float4*>(&tb[4]) = *reinterpret_cast<const float4*>(table16 + i4.y * 8 + 4);
    *reinterpret_cast<float4*>(&tc[0]) = *reinterpret_cast<const float4*>(table16 + i4.z * 8);
    *reinterpret_cast<float4*>(&tc[4]) = *reinterpret_cast<const float4*>(table16 + i4.z * 8 + 4);
    *reinterpret_cast<float4*>(&td[0]) = *reinterpret_cast<const float4*>(table16 + i4.w * 8);
    *reinterpret_cast<float4*>(&td[4]) = *reinterpret_cast<const float4*>(table16 + i4.w * 8 + 4);
#pragma unroll
    for (int wdw = 0; wdw < 16; ++wdw) {
      const float4 m4 = *reinterpret_cast<const float4*>(mask + (size_t)wdw * 262144 + ij0);
      const float b0 = m4.x * LOG2E - CMB_SHIFT;
      const float b1 = m4.y * LOG2E - CMB_SHIFT;
      const float b2 = m4.z * LOG2E - CMB_SHIFT;
      const float b3 = m4.w * LOG2E - CMB_SHIFT;
      u16* outp = cmb + (size_t)wdw * 8 * 262144 + ij0;
#pragma unroll
      for (int h = 0; h < 8; ++h) {
        uint2 o;
        o.x = cvt_pk_bf16(ta[h] + b0, tb[h] + b1);
        o.y = cvt_pk_bf16(tc[h] + b2, td[h] + b3);
        *reinterpret_cast<uint2*>(outp + (size_t)h * 262144) = o;
      }
    }
    return;
  }

  // ---- qkv body (byte-identical logic to R17) ----
  const int flat = blockIdx.x;                  // 0..1535
  const int wrk = (flat & 7) * 192 + (flat >> 3);
  const int bm = wrk / 3;                       // 0..511
  const int bnp = wrk - bm * 3;                 // 0..2 (column pair = 256 cols)
  const int m0 = bm * 128, n0 = bnp * 256;
  const float scl = (bnp == 0) ? QSL : 1.0f;    // pair 0 = q
  u16* dst = bnp == 0 ? qbuf : (bnp == 1 ? kbuf : vbuf);
  const int lane = tid & 63, wid = tid >> 6;
  const int wm = wid >> 1, wn = wid & 1;
  const int lq = lane & 15, g = lane >> 4;
  const f32x4 fz = {0.f, 0.f, 0.f, 0.f};
  f32x4 acc0[4][4], acc1[4][4];
#pragma unroll
  for (int i = 0; i < 4; ++i)
#pragma unroll
    for (int j = 0; j < 4; ++j) { acc0[i][j] = fz; acc1[i][j] = fz; }

  const int r0 = tid >> 3;                      // 0..31
  const int ch = tid & 7;                       // 16B chunk within row
  const int sx = (ch ^ (r0 & 7)) << 3;          // swizzled u16 offset (const: rr*32 keeps row&7)

  float4 ga[4][2];
  auto gloadA = [&](int k0) {
#pragma unroll
    for (int rr = 0; rr < 4; ++rr) {
      const int r = r0 + rr * 32;
      const float* ax = x + (size_t)(m0 + r) * 256 + k0 + ch * 8;
      ga[rr][0] = *reinterpret_cast<const float4*>(ax);
      ga[rr][1] = *reinterpret_cast<const float4*>(ax + 4);
    }
  };

  gloadA(0);
  for (int k0 = 0; k0 < 256; k0 += 64) {
    __syncthreads();  // prior-iter LDS reads done
#pragma unroll
    for (int rr = 0; rr < 4; ++rr) {
      const int r = r0 + rr * 32;
      const float* bx0 = w + (size_t)(n0 + r) * 256 + k0 + ch * 8;
      const float* bx1 = w + (size_t)(n0 + 128 + r) * 256 + k0 + ch * 8;
      const float4 b00 = *reinterpret_cast<const float4*>(bx0);
      const float4 b01 = *reinterpret_cast<const float4*>(bx0 + 4);
      const float4 b10 = *reinterpret_cast<const float4*>(bx1);
      const float4 b11 = *reinterpret_cast<const float4*>(bx1 + 4);
      uint4 pk;
      pk.x = cvt_pk_bf16(ga[rr][0].x, ga[rr][0].y);
      pk.y = cvt_pk_bf16(ga[rr][0].z, ga[rr][0].w);
      pk.z = cvt_pk_bf16(ga[rr][1].x, ga[rr][1].y);
      pk.w = cvt_pk_bf16(ga[rr][1].z, ga[rr][1].w);
      *reinterpret_cast<uint4*>(&As[r * 64 + sx]) = pk;
      pk.x = cvt_pk_bf16(b00.x * scl, b00.y * scl);
      pk.y = cvt_pk_bf16(b00.z * scl, b00.w * scl);
      pk.z = cvt_pk_bf16(b01.x * scl, b01.y * scl);
      pk.w = cvt_pk_bf16(b01.z * scl, b01.w * scl);
      *reinterpret_cast<uint4*>(&Bs0[r * 64 + sx]) = pk;
      pk.x = cvt_pk_bf16(b10.x * scl, b10.y * scl);
      pk.y = cvt_pk_bf16(b10.z * scl, b10.w * scl);
      pk.z = cvt_pk_bf16(b11.x * scl, b11.y * scl);
      pk.w = cvt_pk_bf16(b11.z * scl, b11.w * scl);
      *reinterpret_cast<uint4*>(&Bs1[r * 64 + sx]) = pk;
    }
    __syncthreads();
    if (k0 + 64 < 256) gloadA(k0 + 64);  // prefetch next x-tile under compute
#pragma unroll
    for (int ks = 0; ks < 2; ++ks) {
      bf16x8 xf[4];
#pragma unroll
      for (int mt = 0; mt < 4; ++mt) {
        const int row = wm * 64 + mt * 16 + lq;
        xf[mt] = *reinterpret_cast<const bf16x8*>(
            &As[row * 64 + (((ks * 4 + g) ^ (row & 7)) << 3)]);
      }
#pragma unroll
      for (int nt = 0; nt < 4; ++nt) {
        const int row = wn * 64 + nt * 16 + lq;
        const int off = row * 64 + (((ks * 4 + g) ^ (row & 7)) << 3);
        const bf16x8 wf0 = *reinterpret_cast<const bf16x8*>(&Bs0[off]);
        const bf16x8 wf1 = *reinterpret_cast<const bf16x8*>(&Bs1[off]);
#pragma unroll
        for (int mt = 0; mt < 4; ++mt) {
          acc0[mt][nt] = __builtin_amdgcn_mfma_f32_16x16x32_bf16(
              wf0, xf[mt], acc0[mt][nt], 0, 0, 0);
          acc1[mt][nt] = __builtin_amdgcn_mfma_f32_16x16x32_bf16(
              wf1, xf[mt], acc1[mt][nt], 0, 0, 0);
        }
      }
    }
  }
  // epilogue: scatter both 128-col halves, bf16, into (b,h,i,d)
#pragma unroll
  for (int mt = 0; mt < 4; ++mt) {
    const int m = m0 + wm * 64 + mt * 16 + lq;
    const int b = m >> 9, ii = m & 511;
#pragma unroll
    for (int nt = 0; nt < 4; ++nt) {
      const int nn = wn * 64 + nt * 16 + 4 * g;  // 0..127 within pair
      {
        const int n = n0 + nn;
        const int h = (n & 255) >> 5;
        const int d = n & 31;
        const size_t off = ((size_t)(b * 8 + h) * 512 + ii) * 32 + d;
        uint2 o2;
        o2.x = cvt_pk_bf16(acc0[mt][nt][0], acc0[mt][nt][1]);
        o2.y = cvt_pk_bf16(acc0[mt][nt][2], acc0[mt][nt][3]);
        *reinterpret_cast<uint2*>(dst + off) = o2;
      }
      {
        const int n = n0 + 128 + nn;
        const int h = (n & 255) >> 5;
        const int d = n & 31;
        const size_t off = ((size_t)(b * 8 + h) * 512 + ii) * 32 + d;
        uint2 o2;
        o2.x = cvt_pk_bf16(acc1[mt][nt][0], acc1[mt][nt][1]);
        o2.y = cvt_pk_bf16(acc1[mt][nt][2], acc1[mt][nt][3]);
        *reinterpret_cast<uint2*>(dst + off) = o2;
      }
    }
  }
}

// ---------------- kernel 4: MFMA attention (R6 lineage, FROZEN byte-identical) ----------------
__global__ __launch_bounds__(256, 2) void attn_mfma(
    u16* qbuf,  // in: scaled Q; out: attention output (own rows only)
    const u16* __restrict__ kbuf, const u16* __restrict__ vbuf,
    const u16* __restrict__ cmb) {
  __shared__ u16 Klds[512 * 32];   // row-major keys, XOR-swizzled 16B chunks
  __shared__ u16 Vtlds[32 * 512];  // V transposed [d][n], XOR-swizzled
  const int t = threadIdx.x;
  const int qc = blockIdx.x, h = blockIdx.y;
  const int bz = blockIdx.z;
  const int b = ((bz & 15) << 3) | (bz >> 4);  // co-schedule same (b&15) blocks
  const size_t bh = (size_t)b * 8 + h;
  const u16* kb = kbuf + bh * 16384;
  const u16* vb = vbuf + bh * 16384;

#pragma unroll
  for (int c = 0; c < 8; ++c) {
    const int cid = t + c * 256;
    const int key = cid >> 2, ch = cid & 3;
    const uint4 kd = *reinterpret_cast<const uint4*>(kb + cid * 8);
    const int idx = key * 32 + ((ch * 8) ^ (((key >> 1) & 3) << 3));
    *reinterpret_cast<uint4*>(&Klds[idx]) = kd;
  }
#pragma unroll
  for (int r = 0; r < 2; ++r) {
    const int n = t + r * 256;
    const uint4 v0 = *reinterpret_cast<const uint4*>(vb + n * 32);
    const uint4 v1 = *reinterpret_cast<const uint4*>(vb + n * 32 + 8);
    const uint4 v2 = *reinterpret_cast<const uint4*>(vb + n * 32 + 16);
    const uint4 v3 = *reinterpret_cast<const uint4*>(vb + n * 32 + 24);
    const u32 wv16[16] = {v0.x, v0.y, v0.z, v0.w, v1.x, v1.y, v1.z, v1.w,
                          v2.x, v2.y, v2.z, v2.w, v3.x, v3.y, v3.z, v3.w};
#pragma unroll
    for (int u = 0; u < 16; ++u) {
      const int d0 = 2 * u, d1 = 2 * u + 1;
      Vtlds[d0 * 512 + (n ^ ((d0 & 7) << 3))] = (u16)(wv16[u] & 0xffffu);
      Vtlds[d1 * 512 + (n ^ ((d1 & 7) << 3))] = (u16)(wv16[u] >> 16);
    }
  }
  __syncthreads();

  const int lane = t & 63;
  const int lq = lane & 15, g = lane >> 4;
  const int wv = t >> 6;
  const int q0 = qc * 256 + wv * 64;

  bf16x8 Qf[4];
  u16* qrowbase = qbuf + bh * 16384;
#pragma unroll
  for (int qt = 0; qt < 4; ++qt)
    Qf[qt] = *reinterpret_cast<const bf16x8*>(qrowbase + (q0 + qt * 16 + lq) * 32 + g * 8);

  const u16* cmbp[4];
  const size_t whbase = (size_t)((b & 15) * 8 + h) * 262144;
#pragma unroll
  for (int qt = 0; qt < 4; ++qt)
    cmbp[qt] = cmb + whbase + (size_t)(q0 + qt * 16 + lq) * 512 + 4 * g;

  const f32x4 fzero = {0.f, 0.f, 0.f, 0.f};
  f32x4 o[2][4];
  f32x4 lsum4[4];
#pragma unroll
  for (int qt = 0; qt < 4; ++qt) {
    lsum4[qt] = fzero;
    o[0][qt] = fzero;
    o[1][qt] = fzero;
  }

  for (int j0 = 0; j0 < 512; j0 += 64) {
    bf16x8 Ak[4];
#pragma unroll
    for (int kt = 0; kt < 4; ++kt) {
      const int key = j0 + kt * 16 + lq;
      const int idx = key * 32 + ((g * 8) ^ (((key >> 1) & 3) << 3));
      Ak[kt] = *reinterpret_cast<const bf16x8*>(&Klds[idx]);
    }
    f32x4 s[4][4];
#pragma unroll
    for (int kt = 0; kt < 4; ++kt)
#pragma unroll
      for (int qt = 0; qt < 4; ++qt) {
        const uint2 cc = *reinterpret_cast<const uint2*>(cmbp[qt] + j0 + kt * 16);
        f32x4 ci;
        ci[0] = __uint_as_float((cc.x & 0xffffu) << 16);
        ci[1] = __uint_as_float(cc.x & 0xffff0000u);
        ci[2] = __uint_as_float((cc.y & 0xffffu) << 16);
        ci[3] = __uint_as_float(cc.y & 0xffff0000u);
        s[kt][qt] = __builtin_amdgcn_mfma_f32_16x16x32_bf16(Ak[kt], Qf[qt], ci, 0, 0, 0);
      }
#pragma unroll
    for (int kt = 0; kt < 4; ++kt) {
      bf16x4 Av[2];
#pragma unroll
      for (int dt = 0; dt < 2; ++dt) {
        const int d = dt * 16 + lq;
        const int n0 = j0 + kt * 16 + 4 * g;
        const int idx = d * 512 + (n0 ^ ((d & 7) << 3));
        Av[dt] = *reinterpret_cast<const bf16x4*>(&Vtlds[idx]);
      }
#pragma unroll
      for (int qt = 0; qt < 4; ++qt) {
        f32x4 p = s[kt][qt];
        p[0] = __builtin_amdgcn_exp2f(p[0]);
        p[1] = __builtin_amdgcn_exp2f(p[1]);
        p[2] = __builtin_amdgcn_exp2f(p[2]);
        p[3] = __builtin_amdgcn_exp2f(p[3]);
        lsum4[qt] += p;
        union { u32 u[2]; bf16x4 v; } bp;
        bp.u[0] = cvt_pk_bf16(p[0], p[1]);
        bp.u[1] = cvt_pk_bf16(p[2], p[3]);
        o[0][qt] = __builtin_amdgcn_mfma_f32_16x16x16bf16_1k(Av[0], bp.v, o[0][qt], 0, 0, 0);
        o[1][qt] = __builtin_amdgcn_mfma_f32_16x16x16bf16_1k(Av[1], bp.v, o[1][qt], 0, 0, 0);
      }
    }
  }
#pragma unroll
  for (int qt = 0; qt < 4; ++qt) {
    float l = (lsum4[qt][0] + lsum4[qt][1]) + (lsum4[qt][2] + lsum4[qt][3]);
    l += __shfl_xor(l, 16);
    l += __shfl_xor(l, 32);
    const float inv = 1.0f / l;
    u16* orow = qrowbase + (q0 + qt * 16 + lq) * 32;
#pragma unroll
    for (int dt = 0; dt < 2; ++dt) {
      uint2 w2;
      w2.x = cvt_pk_bf16(o[dt][qt][0] * inv, o[dt][qt][1] * inv);
      w2.y = cvt_pk_bf16(o[dt][qt][2] * inv, o[dt][qt][3] * inv);
      *reinterpret_cast<uint2*>(orow + dt * 16 + 4 * g) = w2;
    }
  }
}

// ---------------- kernel 5: proj GEMM, bf16 MFMA, bn-merged + A&B-prefetch ----------------
__global__ __launch_bounds__(256, 2) void proj_mfma(
    const u16* __restrict__ abuf, const float* __restrict__ w,
    const float* __restrict__ pb, float* __restrict__ out) {
  __shared__ u16 As[128 * 64];
  __shared__ u16 Bs0[128 * 64];
  __shared__ u16 Bs1[128 * 64];
  const int tid = threadIdx.x;
  const int bm = blockIdx.x;  // 0..511
  const int m0 = bm * 128;
  const int lane = tid & 63, wid = tid >> 6;
  const int wm = wid >> 1, wn = wid & 1;
  const int lq = lane & 15, g = lane >> 4;
  const f32x4 fz = {0.f, 0.f, 0.f, 0.f};
  f32x4 acc0[4][4], acc1[4][4];
#pragma unroll
  for (int i = 0; i < 4; ++i)
#pragma unroll
    for (int j = 0; j < 4; ++j) { acc0[i][j] = fz; acc1[i][j] = fz; }

  const int r0 = tid >> 3;
  const int ch = tid & 7;
  const int sx = (ch ^ (r0 & 7)) << 3;
  // A row -> (b, i) decomposition (b uniform per block since 128 | 512)
  const int ab = m0 >> 9;
  const u16* abase = abuf + (size_t)ab * 8 * 16384;
  const int dA0 = (ch & 3) * 8;

  uint4 gaq[4];
  float4 gbq[4][4];  // b00,b01,b10,b11 per rr
  auto gloadA = [&](int k0) {
    const int hA0 = (k0 >> 5) + (ch >> 2);
#pragma unroll
    for (int rr = 0; rr < 4; ++rr) {
      const int r = r0 + rr * 32;
      gaq[rr] = *reinterpret_cast<const uint4*>(
          abase + ((size_t)hA0 * 512 + ((m0 & 511) + r)) * 32 + dA0);
    }
  };
  auto gloadB = [&](int k0) {
#pragma unroll
    for (int rr = 0; rr < 4; ++rr) {
      const int r = r0 + rr * 32;
      const float* bx0 = w + (size_t)r * 256 + k0 + ch * 8;          // n rows 0..127
      const float* bx1 = w + (size_t)(128 + r) * 256 + k0 + ch * 8;  // n rows 128..255
      gbq[rr][0] = *reinterpret_cast<const float4*>(bx0);
      gbq[rr][1] = *reinterpret_cast<const float4*>(bx0 + 4);
      gbq[rr][2] = *reinterpret_cast<const float4*>(bx1);
      gbq[rr][3] = *reinterpret_cast<const float4*>(bx1 + 4);
    }
  };

  gloadA(0);
  gloadB(0);
  for (int k0 = 0; k0 < 256; k0 += 64) {
    __syncthreads();  // prior-iter LDS reads done
#pragma unroll
    for (int rr = 0; rr < 4; ++rr) {
      const int r = r0 + rr * 32;
      *reinterpret_cast<uint4*>(&As[r * 64 + sx]) = gaq[rr];
      uint4 pk;
      pk.x = cvt_pk_bf16(gbq[rr][0].x, gbq[rr][0].y);
      pk.y = cvt_pk_bf16(gbq[rr][0].z, gbq[rr][0].w);
      pk.z = cvt_pk_bf16(gbq[rr][1].x, gbq[rr][1].y);
      pk.w = cvt_pk_bf16(gbq[rr][1].z, gbq[rr][1].w);
      *reinterpret_cast<uint4*>(&Bs0[r * 64 + sx]) = pk;
      pk.x = cvt_pk_bf16(gbq[rr][2].x, gbq[rr][2].y);
      pk.y = cvt_pk_bf16(gbq[rr][2].z, gbq[rr][2].w);
      pk.z = cvt_pk_bf16(gbq[rr][3].x, gbq[rr][3].y);
      pk.w = cvt_pk_bf16(gbq[rr][3].z, gbq[rr][3].w);
      *reinterpret_cast<uint4*>(&Bs1[r * 64 + sx]) = pk;
    }
    __syncthreads();
    if (k0 + 64 < 256) { gloadA(k0 + 64); gloadB(k0 + 64); }  // prefetch under compute
#pragma unroll
    for (int ks = 0; ks < 2; ++ks) {
      bf16x8 xf[4];
#pragma unroll
      for (int mt = 0; mt < 4; ++mt) {
        const int row = wm * 64 + mt * 16 + lq;
        xf[mt] = *reinterpret_cast<const bf16x8*>(
            &As[row * 64 + (((ks * 4 + g) ^ (row & 7)) << 3)]);
      }
#pragma unroll
      for (int nt = 0; nt < 4; ++nt) {
        const int row = wn * 64 + nt * 16 + lq;
        const int off = row * 64 + (((ks * 4 + g) ^ (row & 7)) << 3);
        const bf16x8 wf0 = *reinterpret_cast<const bf16x8*>(&Bs0[off]);
        const bf16x8 wf1 = *reinterpret_cast<const bf16x8*>(&Bs1[off]);
#pragma unroll
        for (int mt = 0; mt < 4; ++mt) {
          acc0[mt][nt] = __builtin_amdgcn_mfma_f32_16x16x32_bf16(
              wf0, xf[mt], acc0[mt][nt], 0, 0, 0);
          acc1[mt][nt] = __builtin_amdgcn_mfma_f32_16x16x32_bf16(
              wf1, xf[mt], acc1[mt][nt], 0, 0, 0);
        }
      }
    }
  }
  // epilogue: f32 out, row-major, +bias (both 128-col halves)
#pragma unroll
  for (int mt = 0; mt < 4; ++mt) {
    const int m = m0 + wm * 64 + mt * 16 + lq;
#pragma unroll
    for (int nt = 0; nt < 4; ++nt) {
      const int n = wn * 64 + nt * 16 + 4 * g;
      const float4 pb0 = *reinterpret_cast<const float4*>(pb + n);
      *reinterpret_cast<float4*>(out + (size_t)m * 256 + n) =
          make_float4(acc0[mt][nt][0] + pb0.x, acc0[mt][nt][1] + pb0.y,
                      acc0[mt][nt][2] + pb0.z, acc0[mt][nt][3] + pb0.w);
      const float4 pb1 = *reinterpret_cast<const float4*>(pb + 128 + n);
      *reinterpret_cast<float4*>(out + (size_t)m * 256 + 128 + n) =
          make_float4(acc1[mt][nt][0] + pb1.x, acc1[mt][nt][1] + pb1.y,
                      acc1[mt][nt][2] + pb1.z, acc1[mt][nt][3] + pb1.w);
    }
  }
}

extern "C" void kernel_launch(void* const* d_in, const int* in_sizes, int n_in,
                              void* d_out, int out_size, void* d_ws, size_t ws_size,
                              hipStream_t stream) {
  const float* x = (const float*)d_in[0];
  const float* mask = (const float*)d_in[1];
  const float* qkv_w = (const float*)d_in[2];
  const float* proj_w = (const float*)d_in[3];
  const float* proj_b = (const float*)d_in[4];
  const float* cpb_w1 = (const float*)d_in[5];
  const float* cpb_b1 = (const float*)d_in[6];
  const float* cpb_w2 = (const float*)d_in[7];
  const float* rpb = (const float*)d_in[8];
  const int* rpb_idx = (const int*)d_in[9];
  float* out = (float*)d_out;

  char* ws = (char*)d_ws;
  u16* qbuf = (u16*)(ws);                       // 33,554,432 B
  u16* kbuf = (u16*)(ws + 33554432);            // 33,554,432 B
  u16* vbuf = (u16*)(ws + 67108864);            // 33,554,432 B
  u16* cmb = (u16*)(ws + 100663296);            // 67,108,864 B
  float* table16 = (float*)(ws + 167772160);    //    108,000 B

  cpb_kernel<<<422, 512, 0, stream>>>(rpb, cpb_w1, cpb_b1, cpb_w2, table16);
  cmb_qkv_fused<<<1792, 256, 0, stream>>>(rpb_idx, table16, mask, cmb,
                                          x, qkv_w, qbuf, kbuf, vbuf);
  attn_mfma<<<dim3(2, 8, 128), 256, 0, stream>>>(qbuf, kbuf, vbuf, cmb);
  proj_mfma<<<512, 256, 0, stream>>>(qbuf, proj_w, proj_b, out);
}

// Round 19
// 249.342 us; speedup vs baseline: 1.0251x; 1.0251x over previous
//
#include <hip/hip_runtime.h>
#include <hip/hip_bf16.h>

// WindowAttention: B=128 windows, N=512, C=256, H=8, D=32.
// Round 19: REVERT to R17 (best passing, 251.8 us). R18's dispatch-order swap
// regressed (-4 us): trailing cmb blocks extend the fused kernel's makespan,
// leading cmb blocks finish inside qkv's shadow. attn FROZEN byte-identical
// (R6 lineage; 4/4 structural edits NaN'd — codegen-sensitive).
// ws layout (bytes):
//   qbuf  bf16 (B,H,N,D)  @ 0           33,554,432  (q pre-scaled by 1/sqrt(32)*log2e; overwritten by attn out)
//   kbuf  bf16 (B,H,N,D)  @ 33,554,432  33,554,432
//   vbuf  bf16 (B,H,N,D)  @ 67,108,864  33,554,432
//   cmb   bf16 (16,8,N,N) @ 100,663,296 67,108,864  (16*sigmoid*log2e + mask*log2e - 11.65, centered)
//   tbl   f32  (3375,8)   @ 167,772,160    108,000
// total ~167.9 MB

using u16 = unsigned short;
using u32 = unsigned int;
typedef short bf16x4 __attribute__((ext_vector_type(4)));
typedef short bf16x8 __attribute__((ext_vector_type(8)));
typedef float f32x4 __attribute__((ext_vector_type(4)));

#define QSL 0.25503471f       // (1/sqrt(32)) * log2(e)
#define LOG2E 1.44269504f
#define CMB_SHIFT 11.65f      // centers bias*log2e (~11.66); softmax shift-invariant

static __device__ __forceinline__ u32 cvt_pk_bf16(float lo, float hi) {
  u32 r;
  asm("v_cvt_pk_bf16_f32 %0, %1, %2" : "=v"(r) : "v"(lo), "v"(hi));
  return r;
}

// ---------------- kernel 1: CPB MLP -> 16*sigmoid*log2e table ----------------
// grid 422: each block computes 8 table rows; w1/b1/w2 slices hoisted out of
// the p-loop (loop-invariant). Same arithmetic per element as before.
__global__ __launch_bounds__(512) void cpb_kernel(
    const float* __restrict__ rpb, const float* __restrict__ w1,
    const float* __restrict__ b1, const float* __restrict__ w2,
    float* __restrict__ table16) {
  __shared__ float hid[512];
  const int p0 = blockIdx.x * 8;  // 0..3368
  const int t = threadIdx.x;      // 0..511
  const float w10 = w1[t * 3 + 0], w11 = w1[t * 3 + 1], w12 = w1[t * 3 + 2];
  const float bb = b1[t];
  const int h = t >> 6, lane = t & 63;  // 8 waves, one head per wave
  float w2r[8];
#pragma unroll
  for (int u = 0; u < 8; ++u) w2r[u] = w2[h * 512 + lane + u * 64];
#pragma unroll
  for (int pp = 0; pp < 8; ++pp) {
    const int p = p0 + pp;
    if (p >= 3375) break;  // uniform within block
    const float r0 = rpb[p * 3 + 0], r1 = rpb[p * 3 + 1], r2 = rpb[p * 3 + 2];
    const float hv = fmaf(r0, w10, fmaf(r1, w11, fmaf(r2, w12, bb)));
    __syncthreads();  // prior iteration's reduce reads of hid done
    hid[t] = fmaxf(hv, 0.0f);
    __syncthreads();
    float s = 0.0f;
#pragma unroll
    for (int u = 0; u < 8; ++u)
      s = fmaf(hid[lane + u * 64], w2r[u], s);
#pragma unroll
    for (int off = 32; off > 0; off >>= 1) s += __shfl_down(s, off);
    if (lane == 0) table16[p * 8 + h] = 23.08312065f / (1.0f + __expf(-s));  // 16*log2e*sigmoid
  }
}

// ---------------- kernel 2: fused cmb + qkv ----------------
// blocks 0..255: cmb (combined centered bias+mask, bf16) — finishes in qkv's shadow.
// blocks 256..1791: qkv GEMM bn-pair merged + A-prefetch.
__global__ __launch_bounds__(256, 2) void cmb_qkv_fused(
    const int* __restrict__ rpb_idx, const float* __restrict__ table16,
    const float* __restrict__ mask, u16* __restrict__ cmb,
    const float* __restrict__ x, const float* __restrict__ w,
    u16* __restrict__ qbuf, u16* __restrict__ kbuf, u16* __restrict__ vbuf) {
  __shared__ u16 As[128 * 64];
  __shared__ u16 Bs0[128 * 64];
  __shared__ u16 Bs1[128 * 64];
  const int tid = threadIdx.x;

  if (blockIdx.x < 256) {
    // ---- cmb body ----
    const int ij0 = (blockIdx.x * 256 + tid) * 4;  // 0..262140
    const int4 i4 = *reinterpret_cast<const int4*>(rpb_idx + ij0);
    float ta[8], tb[8], tc[8], td[8];
    *reinterpret_cast<float4*>(&ta[0]) = *reinterpret_cast<const float4*>(table16 + i4.x * 8);
    *reinterpret_cast<float4*>(&ta[4]) = *reinterpret_cast<const float4*>(table16 + i4.x * 8 + 4);
    *reinterpret_cast<float4*>(&tb[0]) = *reinterpret_cast<const float4*>(table16 + i4.y * 8);
    *reinterpret_cast<float4*>(&tb[4]) = *reinterpret_cast<const float4*>(table16 + i4.y * 8 + 4);
    *reinterpret_cast<float4*>(&tc[0]) = *reinterpret_cast<const float4*>(table16 + i4.z * 8);
    *reinterpret_cast<float4*>(&tc[4]) = *reinterpret_cast<const float4*>(table16 + i4.z * 8 + 4);
    *reinterpret_cast<float4*>(&td[0]) = *reinterpret_cast<const float4*>(table16 + i4.w * 8);
    *reinterpret_cast<float4*>(&td[4]) = *reinterpret_cast<const float4*>(table16 + i4.w * 8 + 4);
#pragma unroll
    for (int wdw = 0; wdw < 16; ++wdw) {
      const float4 m4 = *reinterpret_cast<const float4*>(mask + (size_t)wdw * 262144 + ij0);
      const float b0 = m4.x * LOG2E - CMB_SHIFT;
      const float b1 = m4.y * LOG2E - CMB_SHIFT;
      const float b2 = m4.z * LOG2E - CMB_SHIFT;
      const float b3 = m4.w * LOG2E - CMB_SHIFT;
      u16* outp = cmb + (size_t)wdw * 8 * 262144 + ij0;
#pragma unroll
      for (int h = 0; h < 8; ++h) {
        uint2 o;
        o.x = cvt_pk_bf16(ta[h] + b0, tb[h] + b1);
        o.y = cvt_pk_bf16(tc[h] + b2, td[h] + b3);
        *reinterpret_cast<uint2*>(outp + (size_t)h * 262144) = o;
      }
    }
    return;
  }

  // ---- qkv body ----
  const int flat = blockIdx.x - 256;            // 0..1535
  const int wrk = (flat & 7) * 192 + (flat >> 3);
  const int bm = wrk / 3;                       // 0..511
  const int bnp = wrk - bm * 3;                 // 0..2 (column pair = 256 cols)
  const int m0 = bm * 128, n0 = bnp * 256;
  const float scl = (bnp == 0) ? QSL : 1.0f;    // pair 0 = q
  u16* dst = bnp == 0 ? qbuf : (bnp == 1 ? kbuf : vbuf);
  const int lane = tid & 63, wid = tid >> 6;
  const int wm = wid >> 1, wn = wid & 1;
  const int lq = lane & 15, g = lane >> 4;
  const f32x4 fz = {0.f, 0.f, 0.f, 0.f};
  f32x4 acc0[4][4], acc1[4][4];
#pragma unroll
  for (int i = 0; i < 4; ++i)
#pragma unroll
    for (int j = 0; j < 4; ++j) { acc0[i][j] = fz; acc1[i][j] = fz; }

  const int r0 = tid >> 3;                      // 0..31
  const int ch = tid & 7;                       // 16B chunk within row
  const int sx = (ch ^ (r0 & 7)) << 3;          // swizzled u16 offset (const: rr*32 keeps row&7)

  float4 ga[4][2];
  auto gloadA = [&](int k0) {
#pragma unroll
    for (int rr = 0; rr < 4; ++rr) {
      const int r = r0 + rr * 32;
      const float* ax = x + (size_t)(m0 + r) * 256 + k0 + ch * 8;
      ga[rr][0] = *reinterpret_cast<const float4*>(ax);
      ga[rr][1] = *reinterpret_cast<const float4*>(ax + 4);
    }
  };

  gloadA(0);
  for (int k0 = 0; k0 < 256; k0 += 64) {
    __syncthreads();  // prior-iter LDS reads done
#pragma unroll
    for (int rr = 0; rr < 4; ++rr) {
      const int r = r0 + rr * 32;
      const float* bx0 = w + (size_t)(n0 + r) * 256 + k0 + ch * 8;
      const float* bx1 = w + (size_t)(n0 + 128 + r) * 256 + k0 + ch * 8;
      const float4 b00 = *reinterpret_cast<const float4*>(bx0);
      const float4 b01 = *reinterpret_cast<const float4*>(bx0 + 4);
      const float4 b10 = *reinterpret_cast<const float4*>(bx1);
      const float4 b11 = *reinterpret_cast<const float4*>(bx1 + 4);
      uint4 pk;
      pk.x = cvt_pk_bf16(ga[rr][0].x, ga[rr][0].y);
      pk.y = cvt_pk_bf16(ga[rr][0].z, ga[rr][0].w);
      pk.z = cvt_pk_bf16(ga[rr][1].x, ga[rr][1].y);
      pk.w = cvt_pk_bf16(ga[rr][1].z, ga[rr][1].w);
      *reinterpret_cast<uint4*>(&As[r * 64 + sx]) = pk;
      pk.x = cvt_pk_bf16(b00.x * scl, b00.y * scl);
      pk.y = cvt_pk_bf16(b00.z * scl, b00.w * scl);
      pk.z = cvt_pk_bf16(b01.x * scl, b01.y * scl);
      pk.w = cvt_pk_bf16(b01.z * scl, b01.w * scl);
      *reinterpret_cast<uint4*>(&Bs0[r * 64 + sx]) = pk;
      pk.x = cvt_pk_bf16(b10.x * scl, b10.y * scl);
      pk.y = cvt_pk_bf16(b10.z * scl, b10.w * scl);
      pk.z = cvt_pk_bf16(b11.x * scl, b11.y * scl);
      pk.w = cvt_pk_bf16(b11.z * scl, b11.w * scl);
      *reinterpret_cast<uint4*>(&Bs1[r * 64 + sx]) = pk;
    }
    __syncthreads();
    if (k0 + 64 < 256) gloadA(k0 + 64);  // prefetch next x-tile under compute
#pragma unroll
    for (int ks = 0; ks < 2; ++ks) {
      bf16x8 xf[4];
#pragma unroll
      for (int mt = 0; mt < 4; ++mt) {
        const int row = wm * 64 + mt * 16 + lq;
        xf[mt] = *reinterpret_cast<const bf16x8*>(
            &As[row * 64 + (((ks * 4 + g) ^ (row & 7)) << 3)]);
      }
#pragma unroll
      for (int nt = 0; nt < 4; ++nt) {
        const int row = wn * 64 + nt * 16 + lq;
        const int off = row * 64 + (((ks * 4 + g) ^ (row & 7)) << 3);
        const bf16x8 wf0 = *reinterpret_cast<const bf16x8*>(&Bs0[off]);
        const bf16x8 wf1 = *reinterpret_cast<const bf16x8*>(&Bs1[off]);
#pragma unroll
        for (int mt = 0; mt < 4; ++mt) {
          acc0[mt][nt] = __builtin_amdgcn_mfma_f32_16x16x32_bf16(
              wf0, xf[mt], acc0[mt][nt], 0, 0, 0);
          acc1[mt][nt] = __builtin_amdgcn_mfma_f32_16x16x32_bf16(
              wf1, xf[mt], acc1[mt][nt], 0, 0, 0);
        }
      }
    }
  }
  // epilogue: scatter both 128-col halves, bf16, into (b,h,i,d)
#pragma unroll
  for (int mt = 0; mt < 4; ++mt) {
    const int m = m0 + wm * 64 + mt * 16 + lq;
    const int b = m >> 9, ii = m & 511;
#pragma unroll
    for (int nt = 0; nt < 4; ++nt) {
      const int nn = wn * 64 + nt * 16 + 4 * g;  // 0..127 within pair
      {
        const int n = n0 + nn;
        const int h = (n & 255) >> 5;
        const int d = n & 31;
        const size_t off = ((size_t)(b * 8 + h) * 512 + ii) * 32 + d;
        uint2 o2;
        o2.x = cvt_pk_bf16(acc0[mt][nt][0], acc0[mt][nt][1]);
        o2.y = cvt_pk_bf16(acc0[mt][nt][2], acc0[mt][nt][3]);
        *reinterpret_cast<uint2*>(dst + off) = o2;
      }
      {
        const int n = n0 + 128 + nn;
        const int h = (n & 255) >> 5;
        const int d = n & 31;
        const size_t off = ((size_t)(b * 8 + h) * 512 + ii) * 32 + d;
        uint2 o2;
        o2.x = cvt_pk_bf16(acc1[mt][nt][0], acc1[mt][nt][1]);
        o2.y = cvt_pk_bf16(acc1[mt][nt][2], acc1[mt][nt][3]);
        *reinterpret_cast<uint2*>(dst + off) = o2;
      }
    }
  }
}

// ---------------- kernel 4: MFMA attention (R6 lineage, FROZEN byte-identical) ----------------
__global__ __launch_bounds__(256, 2) void attn_mfma(
    u16* qbuf,  // in: scaled Q; out: attention output (own rows only)
    const u16* __restrict__ kbuf, const u16* __restrict__ vbuf,
    const u16* __restrict__ cmb) {
  __shared__ u16 Klds[512 * 32];   // row-major keys, XOR-swizzled 16B chunks
  __shared__ u16 Vtlds[32 * 512];  // V transposed [d][n], XOR-swizzled
  const int t = threadIdx.x;
  const int qc = blockIdx.x, h = blockIdx.y;
  const int bz = blockIdx.z;
  const int b = ((bz & 15) << 3) | (bz >> 4);  // co-schedule same (b&15) blocks
  const size_t bh = (size_t)b * 8 + h;
  const u16* kb = kbuf + bh * 16384;
  const u16* vb = vbuf + bh * 16384;

#pragma unroll
  for (int c = 0; c < 8; ++c) {
    const int cid = t + c * 256;
    const int key = cid >> 2, ch = cid & 3;
    const uint4 kd = *reinterpret_cast<const uint4*>(kb + cid * 8);
    const int idx = key * 32 + ((ch * 8) ^ (((key >> 1) & 3) << 3));
    *reinterpret_cast<uint4*>(&Klds[idx]) = kd;
  }
#pragma unroll
  for (int r = 0; r < 2; ++r) {
    const int n = t + r * 256;
    const uint4 v0 = *reinterpret_cast<const uint4*>(vb + n * 32);
    const uint4 v1 = *reinterpret_cast<const uint4*>(vb + n * 32 + 8);
    const uint4 v2 = *reinterpret_cast<const uint4*>(vb + n * 32 + 16);
    const uint4 v3 = *reinterpret_cast<const uint4*>(vb + n * 32 + 24);
    const u32 wv16[16] = {v0.x, v0.y, v0.z, v0.w, v1.x, v1.y, v1.z, v1.w,
                          v2.x, v2.y, v2.z, v2.w, v3.x, v3.y, v3.z, v3.w};
#pragma unroll
    for (int u = 0; u < 16; ++u) {
      const int d0 = 2 * u, d1 = 2 * u + 1;
      Vtlds[d0 * 512 + (n ^ ((d0 & 7) << 3))] = (u16)(wv16[u] & 0xffffu);
      Vtlds[d1 * 512 + (n ^ ((d1 & 7) << 3))] = (u16)(wv16[u] >> 16);
    }
  }
  __syncthreads();

  const int lane = t & 63;
  const int lq = lane & 15, g = lane >> 4;
  const int wv = t >> 6;
  const int q0 = qc * 256 + wv * 64;

  bf16x8 Qf[4];
  u16* qrowbase = qbuf + bh * 16384;
#pragma unroll
  for (int qt = 0; qt < 4; ++qt)
    Qf[qt] = *reinterpret_cast<const bf16x8*>(qrowbase + (q0 + qt * 16 + lq) * 32 + g * 8);

  const u16* cmbp[4];
  const size_t whbase = (size_t)((b & 15) * 8 + h) * 262144;
#pragma unroll
  for (int qt = 0; qt < 4; ++qt)
    cmbp[qt] = cmb + whbase + (size_t)(q0 + qt * 16 + lq) * 512 + 4 * g;

  const f32x4 fzero = {0.f, 0.f, 0.f, 0.f};
  f32x4 o[2][4];
  f32x4 lsum4[4];
#pragma unroll
  for (int qt = 0; qt < 4; ++qt) {
    lsum4[qt] = fzero;
    o[0][qt] = fzero;
    o[1][qt] = fzero;
  }

  for (int j0 = 0; j0 < 512; j0 += 64) {
    bf16x8 Ak[4];
#pragma unroll
    for (int kt = 0; kt < 4; ++kt) {
      const int key = j0 + kt * 16 + lq;
      const int idx = key * 32 + ((g * 8) ^ (((key >> 1) & 3) << 3));
      Ak[kt] = *reinterpret_cast<const bf16x8*>(&Klds[idx]);
    }
    f32x4 s[4][4];
#pragma unroll
    for (int kt = 0; kt < 4; ++kt)
#pragma unroll
      for (int qt = 0; qt < 4; ++qt) {
        const uint2 cc = *reinterpret_cast<const uint2*>(cmbp[qt] + j0 + kt * 16);
        f32x4 ci;
        ci[0] = __uint_as_float((cc.x & 0xffffu) << 16);
        ci[1] = __uint_as_float(cc.x & 0xffff0000u);
        ci[2] = __uint_as_float((cc.y & 0xffffu) << 16);
        ci[3] = __uint_as_float(cc.y & 0xffff0000u);
        s[kt][qt] = __builtin_amdgcn_mfma_f32_16x16x32_bf16(Ak[kt], Qf[qt], ci, 0, 0, 0);
      }
#pragma unroll
    for (int kt = 0; kt < 4; ++kt) {
      bf16x4 Av[2];
#pragma unroll
      for (int dt = 0; dt < 2; ++dt) {
        const int d = dt * 16 + lq;
        const int n0 = j0 + kt * 16 + 4 * g;
        const int idx = d * 512 + (n0 ^ ((d & 7) << 3));
        Av[dt] = *reinterpret_cast<const bf16x4*>(&Vtlds[idx]);
      }
#pragma unroll
      for (int qt = 0; qt < 4; ++qt) {
        f32x4 p = s[kt][qt];
        p[0] = __builtin_amdgcn_exp2f(p[0]);
        p[1] = __builtin_amdgcn_exp2f(p[1]);
        p[2] = __builtin_amdgcn_exp2f(p[2]);
        p[3] = __builtin_amdgcn_exp2f(p[3]);
        lsum4[qt] += p;
        union { u32 u[2]; bf16x4 v; } bp;
        bp.u[0] = cvt_pk_bf16(p[0], p[1]);
        bp.u[1] = cvt_pk_bf16(p[2], p[3]);
        o[0][qt] = __builtin_amdgcn_mfma_f32_16x16x16bf16_1k(Av[0], bp.v, o[0][qt], 0, 0, 0);
        o[1][qt] = __builtin_amdgcn_mfma_f32_16x16x16bf16_1k(Av[1], bp.v, o[1][qt], 0, 0, 0);
      }
    }
  }
#pragma unroll
  for (int qt = 0; qt < 4; ++qt) {
    float l = (lsum4[qt][0] + lsum4[qt][1]) + (lsum4[qt][2] + lsum4[qt][3]);
    l += __shfl_xor(l, 16);
    l += __shfl_xor(l, 32);
    const float inv = 1.0f / l;
    u16* orow = qrowbase + (q0 + qt * 16 + lq) * 32;
#pragma unroll
    for (int dt = 0; dt < 2; ++dt) {
      uint2 w2;
      w2.x = cvt_pk_bf16(o[dt][qt][0] * inv, o[dt][qt][1] * inv);
      w2.y = cvt_pk_bf16(o[dt][qt][2] * inv, o[dt][qt][3] * inv);
      *reinterpret_cast<uint2*>(orow + dt * 16 + 4 * g) = w2;
    }
  }
}

// ---------------- kernel 5: proj GEMM, bf16 MFMA, bn-merged + A&B-prefetch ----------------
__global__ __launch_bounds__(256, 2) void proj_mfma(
    const u16* __restrict__ abuf, const float* __restrict__ w,
    const float* __restrict__ pb, float* __restrict__ out) {
  __shared__ u16 As[128 * 64];
  __shared__ u16 Bs0[128 * 64];
  __shared__ u16 Bs1[128 * 64];
  const int tid = threadIdx.x;
  const int bm = blockIdx.x;  // 0..511
  const int m0 = bm * 128;
  const int lane = tid & 63, wid = tid >> 6;
  const int wm = wid >> 1, wn = wid & 1;
  const int lq = lane & 15, g = lane >> 4;
  const f32x4 fz = {0.f, 0.f, 0.f, 0.f};
  f32x4 acc0[4][4], acc1[4][4];
#pragma unroll
  for (int i = 0; i < 4; ++i)
#pragma unroll
    for (int j = 0; j < 4; ++j) { acc0[i][j] = fz; acc1[i][j] = fz; }

  const int r0 = tid >> 3;
  const int ch = tid & 7;
  const int sx = (ch ^ (r0 & 7)) << 3;
  // A row -> (b, i) decomposition (b uniform per block since 128 | 512)
  const int ab = m0 >> 9;
  const u16* abase = abuf + (size_t)ab * 8 * 16384;
  const int dA0 = (ch & 3) * 8;

  uint4 gaq[4];
  float4 gbq[4][4];  // b00,b01,b10,b11 per rr
  auto gloadA = [&](int k0) {
    const int hA0 = (k0 >> 5) + (ch >> 2);
#pragma unroll
    for (int rr = 0; rr < 4; ++rr) {
      const int r = r0 + rr * 32;
      gaq[rr] = *reinterpret_cast<const uint4*>(
          abase + ((size_t)hA0 * 512 + ((m0 & 511) + r)) * 32 + dA0);
    }
  };
  auto gloadB = [&](int k0) {
#pragma unroll
    for (int rr = 0; rr < 4; ++rr) {
      const int r = r0 + rr * 32;
      const float* bx0 = w + (size_t)r * 256 + k0 + ch * 8;          // n rows 0..127
      const float* bx1 = w + (size_t)(128 + r) * 256 + k0 + ch * 8;  // n rows 128..255
      gbq[rr][0] = *reinterpret_cast<const float4*>(bx0);
      gbq[rr][1] = *reinterpret_cast<const float4*>(bx0 + 4);
      gbq[rr][2] = *reinterpret_cast<const float4*>(bx1);
      gbq[rr][3] = *reinterpret_cast<const float4*>(bx1 + 4);
    }
  };

  gloadA(0);
  gloadB(0);
  for (int k0 = 0; k0 < 256; k0 += 64) {
    __syncthreads();  // prior-iter LDS reads done
#pragma unroll
    for (int rr = 0; rr < 4; ++rr) {
      const int r = r0 + rr * 32;
      *reinterpret_cast<uint4*>(&As[r * 64 + sx]) = gaq[rr];
      uint4 pk;
      pk.x = cvt_pk_bf16(gbq[rr][0].x, gbq[rr][0].y);
      pk.y = cvt_pk_bf16(gbq[rr][0].z, gbq[rr][0].w);
      pk.z = cvt_pk_bf16(gbq[rr][1].x, gbq[rr][1].y);
      pk.w = cvt_pk_bf16(gbq[rr][1].z, gbq[rr][1].w);
      *reinterpret_cast<uint4*>(&Bs0[r * 64 + sx]) = pk;
      pk.x = cvt_pk_bf16(gbq[rr][2].x, gbq[rr][2].y);
      pk.y = cvt_pk_bf16(gbq[rr][2].z, gbq[rr][2].w);
      pk.z = cvt_pk_bf16(gbq[rr][3].x, gbq[rr][3].y);
      pk.w = cvt_pk_bf16(gbq[rr][3].z, gbq[rr][3].w);
      *reinterpret_cast<uint4*>(&Bs1[r * 64 + sx]) = pk;
    }
    __syncthreads();
    if (k0 + 64 < 256) { gloadA(k0 + 64); gloadB(k0 + 64); }  // prefetch under compute
#pragma unroll
    for (int ks = 0; ks < 2; ++ks) {
      bf16x8 xf[4];
#pragma unroll
      for (int mt = 0; mt < 4; ++mt) {
        const int row = wm * 64 + mt * 16 + lq;
        xf[mt] = *reinterpret_cast<const bf16x8*>(
            &As[row * 64 + (((ks * 4 + g) ^ (row & 7)) << 3)]);
      }
#pragma unroll
      for (int nt = 0; nt < 4; ++nt) {
        const int row = wn * 64 + nt * 16 + lq;
        const int off = row * 64 + (((ks * 4 + g) ^ (row & 7)) << 3);
        const bf16x8 wf0 = *reinterpret_cast<const bf16x8*>(&Bs0[off]);
        const bf16x8 wf1 = *reinterpret_cast<const bf16x8*>(&Bs1[off]);
#pragma unroll
        for (int mt = 0; mt < 4; ++mt) {
          acc0[mt][nt] = __builtin_amdgcn_mfma_f32_16x16x32_bf16(
              wf0, xf[mt], acc0[mt][nt], 0, 0, 0);
          acc1[mt][nt] = __builtin_amdgcn_mfma_f32_16x16x32_bf16(
              wf1, xf[mt], acc1[mt][nt], 0, 0, 0);
        }
      }
    }
  }
  // epilogue: f32 out, row-major, +bias (both 128-col halves)
#pragma unroll
  for (int mt = 0; mt < 4; ++mt) {
    const int m = m0 + wm * 64 + mt * 16 + lq;
#pragma unroll
    for (int nt = 0; nt < 4; ++nt) {
      const int n = wn * 64 + nt * 16 + 4 * g;
      const float4 pb0 = *reinterpret_cast<const float4*>(pb + n);
      *reinterpret_cast<float4*>(out + (size_t)m * 256 + n) =
          make_float4(acc0[mt][nt][0] + pb0.x, acc0[mt][nt][1] + pb0.y,
                      acc0[mt][nt][2] + pb0.z, acc0[mt][nt][3] + pb0.w);
      const float4 pb1 = *reinterpret_cast<const float4*>(pb + 128 + n);
      *reinterpret_cast<float4*>(out + (size_t)m * 256 + 128 + n) =
          make_float4(acc1[mt][nt][0] + pb1.x, acc1[mt][nt][1] + pb1.y,
                      acc1[mt][nt][2] + pb1.z, acc1[mt][nt][3] + pb1.w);
    }
  }
}

extern "C" void kernel_launch(void* const* d_in, const int* in_sizes, int n_in,
                              void* d_out, int out_size, void* d_ws, size_t ws_size,
                              hipStream_t stream) {
  const float* x = (const float*)d_in[0];
  const float* mask = (const float*)d_in[1];
  const float* qkv_w = (const float*)d_in[2];
  const float* proj_w = (const float*)d_in[3];
  const float* proj_b = (const float*)d_in[4];
  const float* cpb_w1 = (const float*)d_in[5];
  const float* cpb_b1 = (const float*)d_in[6];
  const float* cpb_w2 = (const float*)d_in[7];
  const float* rpb = (const float*)d_in[8];
  const int* rpb_idx = (const int*)d_in[9];
  float* out = (float*)d_out;

  char* ws = (char*)d_ws;
  u16* qbuf = (u16*)(ws);                       // 33,554,432 B
  u16* kbuf = (u16*)(ws + 33554432);            // 33,554,432 B
  u16* vbuf = (u16*)(ws + 67108864);            // 33,554,432 B
  u16* cmb = (u16*)(ws + 100663296);            // 67,108,864 B
  float* table16 = (float*)(ws + 167772160);    //    108,000 B

  cpb_kernel<<<422, 512, 0, stream>>>(rpb, cpb_w1, cpb_b1, cpb_w2, table16);
  cmb_qkv_fused<<<1792, 256, 0, stream>>>(rpb_idx, table16, mask, cmb,
                                          x, qkv_w, qbuf, kbuf, vbuf);
  attn_mfma<<<dim3(2, 8, 128), 256, 0, stream>>>(qbuf, kbuf, vbuf, cmb);
  proj_mfma<<<512, 256, 0, stream>>>(qbuf, proj_w, proj_b, out);
}